// Round 10
// baseline (2661.264 us; speedup 1.0000x reference)
//
#include <hip/hip_runtime.h>
#include <cstdio>

// ============================================================================
// ROUND 24: attention back on LDS (R20 structure) minus its 3 structural
// costs. R23 post-mortem: strided per-lane VMEM gather (16 segs/instr @1KB
// stride) is 2.9x worse than LDS broadcast -> direct-VMEM path abandoned.
// R15/R20 both 463us @ VALUBusy 40% with neither pipe saturated ->
// barrier/latency bound (4 barriers/tile + 3.4e7 V-transpose conflicts).
// Fixes: (1) layouts chosen so K AND V stage as straight row copies
// (convqkv now emits K channel-major, Q/V pixel-major) - zero transpose,
// zero conflict; (2) 3 barriers/tile instead of 4; (3) t+1 loads issued
// after tiles-ready barrier, consumed after PV -> full-phase overlap.
// FMA order identical to R20/R23 -> absmax unchanged.
// ============================================================================

// Keeps the harness-stub identifier name (unused utility).
__global__ __launch_bounds__(256) void CrossModalityPositionAttention_56556129354448_kernel(
    float* dst, float val, int n)
{
  const int i = blockIdx.x * 256 + threadIdx.x;
  if (i < n) dst[i] = val;
}

// ---------------------------------------------------------------------------
// DPP lane-shift helpers (conv halo).
__device__ __forceinline__ float dpp_left(float x) {
  return __int_as_float(__builtin_amdgcn_update_dpp(
      0, __float_as_int(x), 0x111, 0xF, 0xF, true));   // row_shr:1
}
__device__ __forceinline__ float dpp_right(float x) {
  return __int_as_float(__builtin_amdgcn_update_dpp(
      0, __float_as_int(x), 0x101, 0xF, 0xF, true));   // row_shl:1
}

#define CTROWS 18
#define CTSTR  64
#define CTSZ   (CTROWS * CTSTR)   // 1152 floats

// ---------------------------------------------------------------------------
// Fused q/k/v conv3x3 + BN + ReLU.
// Outputs: Q pixel-major [b][4096][64], V pixel-major, K CHANNEL-major
// [b][64][4096] (so attention stages K as straight [c][m] row copies).
__global__ __launch_bounds__(256, 2) void convqkv_f32(
    const float* __restrict__ f1, const float* __restrict__ f2,
    const float* __restrict__ q_w, const float* __restrict__ q_b,
    const float* __restrict__ q_g, const float* __restrict__ q_be,
    const float* __restrict__ q_m, const float* __restrict__ q_va,
    const float* __restrict__ k_w, const float* __restrict__ k_b,
    const float* __restrict__ k_g, const float* __restrict__ k_be,
    const float* __restrict__ k_m, const float* __restrict__ k_va,
    const float* __restrict__ v_w, const float* __restrict__ v_b,
    const float* __restrict__ v_g, const float* __restrict__ v_be,
    const float* __restrict__ v_m, const float* __restrict__ v_va,
    float* __restrict__ qo, float* __restrict__ ko, float* __restrict__ vo)
{
  __shared__ float tA[2][CTSZ];
  __shared__ float tB[2][CTSZ];
  __shared__ float wlds[112];

  const int b   = blockIdx.z;
  const int co0 = blockIdx.y * 2;
  const int y0  = blockIdx.x * 16;
  const int t   = threadIdx.x;
  const int ry  = t >> 4;
  const int xg  = t & 15;
  const int x0  = xg * 4;

  float qs[2], qsh[2], ks[2], ksh[2], vs[2], vsh[2];
  #pragma unroll
  for (int cc = 0; cc < 2; ++cc) {
    const int c = co0 + cc;
    float iv;
    iv = q_g[c] * rsqrtf(q_va[c] + 1e-5f);
    qs[cc] = iv; qsh[cc] = q_b[c] * iv + q_be[c] - q_m[c] * iv;
    iv = k_g[c] * rsqrtf(k_va[c] + 1e-5f);
    ks[cc] = iv; ksh[cc] = k_b[c] * iv + k_be[c] - k_m[c] * iv;
    iv = v_g[c] * rsqrtf(v_va[c] + 1e-5f);
    vs[cc] = iv; vsh[cc] = v_b[c] * iv + v_be[c] - v_m[c] * iv;
  }

  const float* srcA = f1 + (size_t)b * 256 * 4096;
  const float* srcB = f2 + (size_t)b * 256 * 4096;

  float4 rA[2][2], rB[2][2];
  const int row0 = t >> 4;
  const int row1 = 16 + (t >> 4);
  const int grp  = t & 15;

  const int wseg = t / 18;
  const int wkk  = t - wseg * 18;
  const float* wptr = (wseg < 2) ? q_w : ((wseg < 4) ? k_w : v_w);
  const int wbase0 = (co0 + (wseg & 1)) * 256 * 9 + wkk;
  float wreg = 0.f;

  #define LOADREGS(R)                                                         \
    {                                                                         \
      _Pragma("unroll")                                                       \
      for (int s = 0; s < 2; ++s) {                                           \
        const size_t cb = (size_t)((R) * 2 + s) * 4096;                       \
        {                                                                     \
          const int gy = y0 - 1 + row0;                                       \
          float4 a = make_float4(0.f, 0.f, 0.f, 0.f);                         \
          float4 bb = make_float4(0.f, 0.f, 0.f, 0.f);                        \
          if (gy >= 0 && gy <= 63) {                                          \
            a  = *(const float4*)(srcA + cb + gy * 64 + grp * 4);             \
            bb = *(const float4*)(srcB + cb + gy * 64 + grp * 4);             \
          }                                                                   \
          rA[s][0] = a; rB[s][0] = bb;                                        \
        }                                                                     \
        if (t < 32) {                                                         \
          const int gy = y0 - 1 + row1;                                       \
          float4 a = make_float4(0.f, 0.f, 0.f, 0.f);                         \
          float4 bb = make_float4(0.f, 0.f, 0.f, 0.f);                        \
          if (gy >= 0 && gy <= 63) {                                          \
            a  = *(const float4*)(srcA + cb + gy * 64 + grp * 4);             \
            bb = *(const float4*)(srcB + cb + gy * 64 + grp * 4);             \
          }                                                                   \
          rA[s][1] = a; rB[s][1] = bb;                                        \
        }                                                                     \
      }                                                                       \
      if (t < 108) wreg = wptr[wbase0 + (R) * 18];                            \
    }

  float accQ[2][4] = {{0.f}}, accK[2][4] = {{0.f}}, accV[2][4] = {{0.f}};

  LOADREGS(0);

  for (int r = 0; r < 128; ++r) {
    __syncthreads();
    #pragma unroll
    for (int s = 0; s < 2; ++s) {
      *(float4*)(&tA[s][row0 * CTSTR + grp * 4]) = rA[s][0];
      *(float4*)(&tB[s][row0 * CTSTR + grp * 4]) = rB[s][0];
      if (t < 32) {
        *(float4*)(&tA[s][row1 * CTSTR + grp * 4]) = rA[s][1];
        *(float4*)(&tB[s][row1 * CTSTR + grp * 4]) = rB[s][1];
      }
    }
    if (t < 108) wlds[t] = wreg;
    __syncthreads();
    if (r < 127) LOADREGS(r + 1);

    #pragma unroll
    for (int s = 0; s < 2; ++s) {
      #pragma unroll
      for (int ky = 0; ky < 3; ++ky) {
        const float4 a4 = *(const float4*)(&tA[s][(ry + ky) * CTSTR + x0]);
        const float4 b4 = *(const float4*)(&tB[s][(ry + ky) * CTSTR + x0]);
        const float ca[6] = {dpp_left(a4.w), a4.x, a4.y, a4.z, a4.w, dpp_right(a4.x)};
        const float cb[6] = {dpp_left(b4.w), b4.x, b4.y, b4.z, b4.w, dpp_right(b4.x)};
        #pragma unroll
        for (int cc = 0; cc < 2; ++cc) {
          const int wb = cc * 18 + s * 9 + ky * 3;
          const float q0 = wlds[wb],      q1 = wlds[wb + 1],      q2 = wlds[wb + 2];
          const float k0 = wlds[36 + wb], k1 = wlds[36 + wb + 1], k2 = wlds[36 + wb + 2];
          const float v0 = wlds[72 + wb], v1 = wlds[72 + wb + 1], v2 = wlds[72 + wb + 2];
          #pragma unroll
          for (int px = 0; px < 4; ++px) {
            accQ[cc][px] += cb[px] * q0 + cb[px + 1] * q1 + cb[px + 2] * q2;
            accK[cc][px] += ca[px] * k0 + ca[px + 1] * k1 + ca[px + 2] * k2;
            accV[cc][px] += ca[px] * v0 + ca[px + 1] * v1 + ca[px + 2] * v2;
          }
        }
      }
    }
  }

  // epilogue: BN + ReLU.  Q,V pixel-major float2; K channel-major float4.
  const size_t pb = (size_t)b * 4096 + (size_t)(y0 + ry) * 64 + x0;
  #pragma unroll
  for (int px = 0; px < 4; ++px) {
    const size_t o8 = (pb + px) * 64 + co0;
    float2 o2;
    o2.x = fmaxf(accQ[0][px] * qs[0] + qsh[0], 0.f);
    o2.y = fmaxf(accQ[1][px] * qs[1] + qsh[1], 0.f);
    *(float2*)(qo + o8) = o2;
    o2.x = fmaxf(accV[0][px] * vs[0] + vsh[0], 0.f);
    o2.y = fmaxf(accV[1][px] * vs[1] + vsh[1], 0.f);
    *(float2*)(vo + o8) = o2;
  }
  const size_t kb0 = ((size_t)b * 64 + co0) * 4096 + (size_t)(y0 + ry) * 64 + x0;
  #pragma unroll
  for (int cc = 0; cc < 2; ++cc) {
    float4 o;
    o.x = fmaxf(accK[cc][0] * ks[cc] + ksh[cc], 0.f);
    o.y = fmaxf(accK[cc][1] * ks[cc] + ksh[cc], 0.f);
    o.z = fmaxf(accK[cc][2] * ks[cc] + ksh[cc], 0.f);
    o.w = fmaxf(accK[cc][3] * ks[cc] + ksh[cc], 0.f);
    *(float4*)(ko + kb0 + (size_t)cc * 4096) = o;
  }
}

// ---------------------------------------------------------------------------
// Flash attention, fp32. Q pixel-major, K channel-major, V pixel-major;
// f channel-major. 32 q/block, grid 512 (2/CU; LDS 51KB allows 3).
// Thread (mg=t&15, ng=t>>4): rows 2ng+{0,1}; QK m-cols & PV c-cols 4mg+{0..3}.
// LDS: Q[32][68], P[32][68], K[c][m] [64][68], V[m][c] [64][68] - all staged
// as straight row copies (no transpose), all access 2-way/broadcast (free).
// 3 barriers/tile; t+1 loads in flight across the whole compute phase.
__global__ __launch_bounds__(256, 2) void attention_flash_f32(
    const float* __restrict__ q, const float* __restrict__ k,
    const float* __restrict__ v, float* __restrict__ f)
{
  __shared__ float qt[32 * 68];
  __shared__ float pt[32 * 68];
  __shared__ float kt[64 * 68];
  __shared__ float vt[64 * 68];

  const int lin = blockIdx.x;
  const int b  = (lin & 7) >> 1;
  const int nb = ((lin >> 3) << 1) | (lin & 1);
  const int n0 = nb * 32;

  const int t = threadIdx.x;
  const int mg = t & 15;
  const int ng = t >> 4;

  const float* qb = q + (size_t)b * 4096 * 64;   // pixel-major
  const float* kb = k + (size_t)b * 64 * 4096;   // channel-major
  const float* vb = v + (size_t)b * 4096 * 64;   // pixel-major

  // ---- stage Q rows [n][c]
  {
    const int row = t >> 3;
    const int c8 = (t & 7) * 8;
    const float4 a0 = *(const float4*)(qb + (size_t)(n0 + row) * 64 + c8);
    const float4 a1 = *(const float4*)(qb + (size_t)(n0 + row) * 64 + c8 + 4);
    *(float4*)(qt + row * 68 + c8)     = a0;
    *(float4*)(qt + row * 68 + c8 + 4) = a1;
  }

  // staging maps: K row c = t>>2 (channel-major row), V row m = t>>2
  const int sr = t >> 2;
  const int sf = t & 3;

  float4 kreg[4], vreg[4];
  #pragma unroll
  for (int r = 0; r < 4; ++r) {
    kreg[r] = *(const float4*)(kb + (size_t)sr * 4096 + (sf + 4 * r) * 4);
    vreg[r] = *(const float4*)(vb + (size_t)sr * 64 + (sf + 4 * r) * 4);
  }
  #pragma unroll
  for (int r = 0; r < 4; ++r) {
    *(float4*)(kt + sr * 68 + (sf + 4 * r) * 4) = kreg[r];
    *(float4*)(vt + sr * 68 + (sf + 4 * r) * 4) = vreg[r];
  }
  __syncthreads();   // barrier A (tile 0 ready; Q ready)

  float4 o0 = make_float4(0.f, 0.f, 0.f, 0.f);
  float4 o1 = make_float4(0.f, 0.f, 0.f, 0.f);
  float m0r = -1e30f, m1r = -1e30f, l0 = 0.f, l1 = 0.f;

  const float* qrow0 = qt + (2 * ng + 0) * 68;
  const float* qrow1 = qt + (2 * ng + 1) * 68;
  float* prow0 = pt + (2 * ng + 0) * 68;
  float* prow1 = pt + (2 * ng + 1) * 68;

  for (int tile = 0; tile < 64; ++tile) {
    // prefetch t+1 (consumed after PV -> overlaps whole compute phase)
    if (tile < 63) {
      const int m0 = (tile + 1) * 64;
      #pragma unroll
      for (int r = 0; r < 4; ++r) {
        kreg[r] = *(const float4*)(kb + (size_t)sr * 4096 + m0 + (sf + 4 * r) * 4);
        vreg[r] = *(const float4*)(vb + (size_t)(m0 + sr) * 64 + (sf + 4 * r) * 4);
      }
    }

    // ---- QK: s[i][j] += Q[2ng+i][c] * K[c][4mg+j], c ascending
    float s00 = 0.f, s01 = 0.f, s02 = 0.f, s03 = 0.f;
    float s10 = 0.f, s11 = 0.f, s12 = 0.f, s13 = 0.f;
    #pragma unroll
    for (int c4 = 0; c4 < 16; ++c4) {
      const float4 qa = *(const float4*)(qrow0 + c4 * 4);
      const float4 qc = *(const float4*)(qrow1 + c4 * 4);
      const float4 kA = *(const float4*)(kt + (4 * c4 + 0) * 68 + 4 * mg);
      const float4 kB = *(const float4*)(kt + (4 * c4 + 1) * 68 + 4 * mg);
      const float4 kC = *(const float4*)(kt + (4 * c4 + 2) * 68 + 4 * mg);
      const float4 kD = *(const float4*)(kt + (4 * c4 + 3) * 68 + 4 * mg);
      s00 = fmaf(qa.w, kD.x, fmaf(qa.z, kC.x, fmaf(qa.y, kB.x, fmaf(qa.x, kA.x, s00))));
      s01 = fmaf(qa.w, kD.y, fmaf(qa.z, kC.y, fmaf(qa.y, kB.y, fmaf(qa.x, kA.y, s01))));
      s02 = fmaf(qa.w, kD.z, fmaf(qa.z, kC.z, fmaf(qa.y, kB.z, fmaf(qa.x, kA.z, s02))));
      s03 = fmaf(qa.w, kD.w, fmaf(qa.z, kC.w, fmaf(qa.y, kB.w, fmaf(qa.x, kA.w, s03))));
      s10 = fmaf(qc.w, kD.x, fmaf(qc.z, kC.x, fmaf(qc.y, kB.x, fmaf(qc.x, kA.x, s10))));
      s11 = fmaf(qc.w, kD.y, fmaf(qc.z, kC.y, fmaf(qc.y, kB.y, fmaf(qc.x, kA.y, s11))));
      s12 = fmaf(qc.w, kD.z, fmaf(qc.z, kC.z, fmaf(qc.y, kB.z, fmaf(qc.x, kA.z, s12))));
      s13 = fmaf(qc.w, kD.w, fmaf(qc.z, kC.w, fmaf(qc.y, kB.w, fmaf(qc.x, kA.w, s13))));
    }

    // ---- online softmax (across 16 mg-lanes, intra-wave)
    float rm0 = fmaxf(fmaxf(s00, s01), fmaxf(s02, s03));
    rm0 = fmaxf(rm0, __shfl_xor(rm0, 1));
    rm0 = fmaxf(rm0, __shfl_xor(rm0, 2));
    rm0 = fmaxf(rm0, __shfl_xor(rm0, 4));
    rm0 = fmaxf(rm0, __shfl_xor(rm0, 8));
    float rm1 = fmaxf(fmaxf(s10, s11), fmaxf(s12, s13));
    rm1 = fmaxf(rm1, __shfl_xor(rm1, 1));
    rm1 = fmaxf(rm1, __shfl_xor(rm1, 2));
    rm1 = fmaxf(rm1, __shfl_xor(rm1, 4));
    rm1 = fmaxf(rm1, __shfl_xor(rm1, 8));

    const float mn0 = fmaxf(m0r, rm0);
    const float mn1 = fmaxf(m1r, rm1);
    const float al0 = __expf(m0r - mn0);
    const float al1 = __expf(m1r - mn1);
    m0r = mn0; m1r = mn1;

    const float p00 = __expf(s00 - mn0), p01 = __expf(s01 - mn0);
    const float p02 = __expf(s02 - mn0), p03 = __expf(s03 - mn0);
    const float p10 = __expf(s10 - mn1), p11 = __expf(s11 - mn1);
    const float p12 = __expf(s12 - mn1), p13 = __expf(s13 - mn1);

    float rs0 = p00 + p01 + p02 + p03;
    rs0 += __shfl_xor(rs0, 1);
    rs0 += __shfl_xor(rs0, 2);
    rs0 += __shfl_xor(rs0, 4);
    rs0 += __shfl_xor(rs0, 8);
    float rs1 = p10 + p11 + p12 + p13;
    rs1 += __shfl_xor(rs1, 1);
    rs1 += __shfl_xor(rs1, 2);
    rs1 += __shfl_xor(rs1, 4);
    rs1 += __shfl_xor(rs1, 8);
    l0 = al0 * l0 + rs0;
    l1 = al1 * l1 + rs1;

    // ---- P exchange (prior PV-reads of pt are fenced by barriers D+A)
    *(float4*)(prow0 + 4 * mg) = make_float4(p00, p01, p02, p03);
    *(float4*)(prow1 + 4 * mg) = make_float4(p10, p11, p12, p13);
    __syncthreads();   // barrier C: P visible

    // ---- rescale O
    o0.x *= al0; o0.y *= al0; o0.z *= al0; o0.w *= al0;
    o1.x *= al1; o1.y *= al1; o1.z *= al1; o1.w *= al1;

    // ---- PV: o[i][j] += sum_m P[2ng+i][m] * V[m][4mg+j], m ascending
    #pragma unroll
    for (int m4 = 0; m4 < 16; ++m4) {
      const float4 pa = *(const float4*)(prow0 + m4 * 4);
      const float4 pc = *(const float4*)(prow1 + m4 * 4);
      const float4 v0 = *(const float4*)(vt + (4 * m4 + 0) * 68 + 4 * mg);
      const float4 v1 = *(const float4*)(vt + (4 * m4 + 1) * 68 + 4 * mg);
      const float4 v2 = *(const float4*)(vt + (4 * m4 + 2) * 68 + 4 * mg);
      const float4 v3 = *(const float4*)(vt + (4 * m4 + 3) * 68 + 4 * mg);
      o0.x = fmaf(pa.w, v3.x, fmaf(pa.z, v2.x, fmaf(pa.y, v1.x, fmaf(pa.x, v0.x, o0.x))));
      o0.y = fmaf(pa.w, v3.y, fmaf(pa.z, v2.y, fmaf(pa.y, v1.y, fmaf(pa.x, v0.y, o0.y))));
      o0.z = fmaf(pa.w, v3.z, fmaf(pa.z, v2.z, fmaf(pa.y, v1.z, fmaf(pa.x, v0.z, o0.z))));
      o0.w = fmaf(pa.w, v3.w, fmaf(pa.z, v2.w, fmaf(pa.y, v1.w, fmaf(pa.x, v0.w, o0.w))));
      o1.x = fmaf(pc.w, v3.x, fmaf(pc.z, v2.x, fmaf(pc.y, v1.x, fmaf(pc.x, v0.x, o1.x))));
      o1.y = fmaf(pc.w, v3.y, fmaf(pc.z, v2.y, fmaf(pc.y, v1.y, fmaf(pc.x, v0.y, o1.y))));
      o1.z = fmaf(pc.w, v3.z, fmaf(pc.z, v2.z, fmaf(pc.y, v1.z, fmaf(pc.x, v0.z, o1.z))));
      o1.w = fmaf(pc.w, v3.w, fmaf(pc.z, v2.w, fmaf(pc.y, v1.w, fmaf(pc.x, v0.w, o1.w))));
    }
    __syncthreads();   // barrier D: K/V/P reads of this tile done

    if (tile < 63) {
      #pragma unroll
      for (int r = 0; r < 4; ++r) {
        *(float4*)(kt + sr * 68 + (sf + 4 * r) * 4) = kreg[r];
        *(float4*)(vt + sr * 68 + (sf + 4 * r) * 4) = vreg[r];
      }
    }
    __syncthreads();   // barrier A: next tile ready
  }

  // ---- epilogue: normalize, transpose via kt ([64][36]), coalesced store
  const float inv0 = 1.f / l0;
  const float inv1 = 1.f / l1;
  {
    const int c0 = 4 * mg;
    kt[(c0 + 0) * 36 + 2 * ng + 0] = o0.x * inv0;
    kt[(c0 + 1) * 36 + 2 * ng + 0] = o0.y * inv0;
    kt[(c0 + 2) * 36 + 2 * ng + 0] = o0.z * inv0;
    kt[(c0 + 3) * 36 + 2 * ng + 0] = o0.w * inv0;
    kt[(c0 + 0) * 36 + 2 * ng + 1] = o1.x * inv1;
    kt[(c0 + 1) * 36 + 2 * ng + 1] = o1.y * inv1;
    kt[(c0 + 2) * 36 + 2 * ng + 1] = o1.z * inv1;
    kt[(c0 + 3) * 36 + 2 * ng + 1] = o1.w * inv1;
  }
  __syncthreads();
  {
    const int c = t >> 2;
    #pragma unroll
    for (int r = 0; r < 2; ++r) {
      const int f4i = (t & 3) + 4 * r;
      *(float4*)(f + ((size_t)b * 64 + c) * 4096 + n0 + f4i * 4) =
          *(const float4*)(kt + c * 36 + f4i * 4);
    }
  }
}

// ---------------------------------------------------------------------------
// conv_r (unchanged; fin is [b][64 c][4096 px]).
__global__ __launch_bounds__(256, 4) void conv_r_f32(
    const float* __restrict__ fin, const float* __restrict__ w,
    const float* __restrict__ bi, const float* __restrict__ g,
    const float* __restrict__ be, const float* __restrict__ mu,
    const float* __restrict__ va, const float* __restrict__ res,
    float* __restrict__ out)
{
  __shared__ float tA[2][CTSZ];
  __shared__ float wlds[80];

  const int b   = blockIdx.z;
  const int co0 = blockIdx.y * 4;
  const int y0  = blockIdx.x * 16;
  const int t   = threadIdx.x;
  const int ry  = t >> 4;
  const int xg  = t & 15;
  const int x0  = xg * 4;

  float sc[4], sh[4];
  #pragma unroll
  for (int cc = 0; cc < 4; ++cc) {
    const int c = co0 + cc;
    const float iv = g[c] * rsqrtf(va[c] + 1e-5f);
    sc[cc] = iv; sh[cc] = bi[c] * iv + be[c] - mu[c] * iv;
  }

  const float* srcA = fin + (size_t)b * 64 * 4096;
  float4 rA[2][2];
  const int row0 = t >> 4;
  const int row1 = 16 + (t >> 4);
  const int grp  = t & 15;

  const int wseg = t / 18;
  const int wkk  = t - wseg * 18;
  const int wbase0 = (co0 + wseg) * 64 * 9 + wkk;
  float wreg = 0.f;

  #define LOADR(R)                                                            \
    {                                                                         \
      _Pragma("unroll")                                                       \
      for (int s = 0; s < 2; ++s) {                                           \
        const size_t cb = (size_t)((R) * 2 + s) * 4096;                       \
        {                                                                     \
          const int gy = y0 - 1 + row0;                                       \
          float4 a = make_float4(0.f, 0.f, 0.f, 0.f);                         \
          if (gy >= 0 && gy <= 63)                                            \
            a = *(const float4*)(srcA + cb + gy * 64 + grp * 4);              \
          rA[s][0] = a;                                                       \
        }                                                                     \
        if (t < 32) {                                                         \
          const int gy = y0 - 1 + row1;                                       \
          float4 a = make_float4(0.f, 0.f, 0.f, 0.f);                         \
          if (gy >= 0 && gy <= 63)                                            \
            a = *(const float4*)(srcA + cb + gy * 64 + grp * 4);              \
          rA[s][1] = a;                                                       \
        }                                                                     \
      }                                                                       \
      if (t < 72) wreg = w[wbase0 + (R) * 18];                                \
    }

  float acc[4][4] = {{0.f}};
  LOADR(0);

  for (int r = 0; r < 32; ++r) {
    __syncthreads();
    #pragma unroll
    for (int s = 0; s < 2; ++s) {
      *(float4*)(&tA[s][row0 * CTSTR + grp * 4]) = rA[s][0];
      if (t < 32)
        *(float4*)(&tA[s][row1 * CTSTR + grp * 4]) = rA[s][1];
    }
    if (t < 72) wlds[t] = wreg;
    __syncthreads();
    if (r < 31) LOADR(r + 1);

    #pragma unroll
    for (int s = 0; s < 2; ++s) {
      #pragma unroll
      for (int ky = 0; ky < 3; ++ky) {
        const float4 a4 = *(const float4*)(&tA[s][(ry + ky) * CTSTR + x0]);
        const float ca[6] = {dpp_left(a4.w), a4.x, a4.y, a4.z, a4.w, dpp_right(a4.x)};
        #pragma unroll
        for (int cc = 0; cc < 4; ++cc) {
          const int wb = cc * 18 + s * 9 + ky * 3;
          const float w0 = wlds[wb], w1 = wlds[wb + 1], w2 = wlds[wb + 2];
          #pragma unroll
          for (int px = 0; px < 4; ++px)
            acc[cc][px] += ca[px] * w0 + ca[px + 1] * w1 + ca[px + 2] * w2;
        }
      }
    }
  }

  const size_t ob = ((size_t)b * 256 + co0) * 4096 + (size_t)(y0 + ry) * 64 + x0;
  #pragma unroll
  for (int cc = 0; cc < 4; ++cc) {
    const float4 rv = *(const float4*)(res + ob + (size_t)cc * 4096);
    float4 o;
    o.x = rv.x + fmaxf(acc[cc][0] * sc[cc] + sh[cc], 0.f);
    o.y = rv.y + fmaxf(acc[cc][1] * sc[cc] + sh[cc], 0.f);
    o.z = rv.z + fmaxf(acc[cc][2] * sc[cc] + sh[cc], 0.f);
    o.w = rv.w + fmaxf(acc[cc][3] * sc[cc] + sh[cc], 0.f);
    *(float4*)(out + ob + (size_t)cc * 4096) = o;
  }
}

// ---------------------------------------------------------------------------
extern "C" void kernel_launch(void* const* d_in, const int* in_sizes, int n_in,
                              void* d_out, int out_size, void* d_ws, size_t ws_size,
                              hipStream_t stream) {
  const float* f1 = (const float*)d_in[0];
  const float* f2 = (const float*)d_in[1];
  const float* qw = (const float*)d_in[2];  const float* qb = (const float*)d_in[3];
  const float* qg = (const float*)d_in[4];  const float* qbe = (const float*)d_in[5];
  const float* qm = (const float*)d_in[6];  const float* qv = (const float*)d_in[7];
  const float* kw = (const float*)d_in[8];  const float* kb = (const float*)d_in[9];
  const float* kg = (const float*)d_in[10]; const float* kbe = (const float*)d_in[11];
  const float* km = (const float*)d_in[12]; const float* kv = (const float*)d_in[13];
  const float* vw = (const float*)d_in[14]; const float* vb = (const float*)d_in[15];
  const float* vg = (const float*)d_in[16]; const float* vbe = (const float*)d_in[17];
  const float* vm = (const float*)d_in[18]; const float* vv = (const float*)d_in[19];
  const float* rw = (const float*)d_in[20]; const float* rb = (const float*)d_in[21];
  const float* rg = (const float*)d_in[22]; const float* rbe = (const float*)d_in[23];
  const float* rm = (const float*)d_in[24]; const float* rv = (const float*)d_in[25];

  hipStreamCaptureStatus cap = hipStreamCaptureStatusNone;
  unsigned long long capid = 0;
  const hipError_t ce = hipStreamGetCaptureInfo(stream, &cap, &capid);
  const bool capturing = (ce == hipSuccess) && (cap != hipStreamCaptureStatusNone);

  // Workspace: q,v pixel-major; k channel-major; f channel-major. 4 MB each.
  const size_t SZ1 = (size_t)4 * 64 * 4096 * 4;
  float* qp = (float*)d_ws;
  float* kp = (float*)((char*)d_ws + SZ1);
  float* vp = (float*)((char*)d_ws + 2 * SZ1);
  float* fp = (float*)((char*)d_ws + 3 * SZ1);

  convqkv_f32<<<dim3(4, 32, 4), 256, 0, stream>>>(
      f1, f2,
      qw, qb, qg, qbe, qm, qv,
      kw, kb, kg, kbe, km, kv,
      vw, vb, vg, vbe, vm, vv,
      qp, kp, vp);
  attention_flash_f32<<<dim3(512), 256, 0, stream>>>(qp, kp, vp, fp);
  conv_r_f32<<<dim3(4, 64, 4), 256, 0, stream>>>(fp, rw, rb, rg, rbe, rm, rv,
                                                 f1, (float*)d_out);

  if (!capturing) {
    const hipError_t le = hipGetLastError();
    const hipError_t se = hipStreamSynchronize(stream);
    float h[4] = {0, 0, 0, 0};
    (void)hipMemcpy(h, d_out, 16, hipMemcpyDeviceToHost);
    fprintf(stderr,
        "ATHENA_R24 lds-native-layouts le=%d sync=%d out=[%g %g %g %g]\n",
        (int)le, (int)se, h[0], h[1], h[2], h[3]);
    fflush(stderr);
  }
}

// Round 11
// 977.647 us; speedup vs baseline: 2.7221x; 2.7221x over previous
//
#include <hip/hip_runtime.h>
#include <cstdio>

// ============================================================================
// ROUND 25: surgical fix on R20 (the verified 463us/VGPR-68 attention).
// R21-R24 post-mortem: all four attention restructures spilled or hit the
// VMEM-gather wall (1334-3396us). Rule learned: don't restructure the loop.
// R20's one proven defect: SQ_LDS_BANK_CONFLICT 3.38e7 from V-transpose
// scalar writes (272-float lane stride -> 8-way), ~30% of the LDS-pipe time
// that bounds the kernel. Fix with ZERO loop changes: convqkv emits V
// PIXEL-major ([b][4096][64]) so attention stages vt[m][c] as straight row
// copies (same conflict-free pattern as K staging). Same tile contents, same
// FMA order, same barriers -> absmax unchanged. Q,K stay channel-major.
// ============================================================================

// Keeps the harness-stub identifier name (unused utility).
__global__ __launch_bounds__(256) void CrossModalityPositionAttention_56556129354448_kernel(
    float* dst, float val, int n)
{
  const int i = blockIdx.x * 256 + threadIdx.x;
  if (i < n) dst[i] = val;
}

// ---------------------------------------------------------------------------
// DPP lane-shift helpers (conv halo).
__device__ __forceinline__ float dpp_left(float x) {
  return __int_as_float(__builtin_amdgcn_update_dpp(
      0, __float_as_int(x), 0x111, 0xF, 0xF, true));   // row_shr:1
}
__device__ __forceinline__ float dpp_right(float x) {
  return __int_as_float(__builtin_amdgcn_update_dpp(
      0, __float_as_int(x), 0x101, 0xF, 0xF, true));   // row_shl:1
}

#define CTROWS 18
#define CTSTR  64
#define CTSZ   (CTROWS * CTSTR)   // 1152 floats

// ---------------------------------------------------------------------------
// Fused q/k/v conv3x3 + BN + ReLU (R19/R20 body).
// Outputs: Q channel-major [b][64][4096], K channel-major, V PIXEL-major
// [b][4096][64] (so attention stages V as straight [m][c] row copies).
__global__ __launch_bounds__(256, 2) void convqkv_f32(
    const float* __restrict__ f1, const float* __restrict__ f2,
    const float* __restrict__ q_w, const float* __restrict__ q_b,
    const float* __restrict__ q_g, const float* __restrict__ q_be,
    const float* __restrict__ q_m, const float* __restrict__ q_va,
    const float* __restrict__ k_w, const float* __restrict__ k_b,
    const float* __restrict__ k_g, const float* __restrict__ k_be,
    const float* __restrict__ k_m, const float* __restrict__ k_va,
    const float* __restrict__ v_w, const float* __restrict__ v_b,
    const float* __restrict__ v_g, const float* __restrict__ v_be,
    const float* __restrict__ v_m, const float* __restrict__ v_va,
    float* __restrict__ qo, float* __restrict__ ko, float* __restrict__ vo)
{
  __shared__ float tA[2][CTSZ];
  __shared__ float tB[2][CTSZ];
  __shared__ float wlds[112];

  const int b   = blockIdx.z;
  const int co0 = blockIdx.y * 2;
  const int y0  = blockIdx.x * 16;
  const int t   = threadIdx.x;
  const int ry  = t >> 4;
  const int xg  = t & 15;
  const int x0  = xg * 4;

  float qs[2], qsh[2], ks[2], ksh[2], vs[2], vsh[2];
  #pragma unroll
  for (int cc = 0; cc < 2; ++cc) {
    const int c = co0 + cc;
    float iv;
    iv = q_g[c] * rsqrtf(q_va[c] + 1e-5f);
    qs[cc] = iv; qsh[cc] = q_b[c] * iv + q_be[c] - q_m[c] * iv;
    iv = k_g[c] * rsqrtf(k_va[c] + 1e-5f);
    ks[cc] = iv; ksh[cc] = k_b[c] * iv + k_be[c] - k_m[c] * iv;
    iv = v_g[c] * rsqrtf(v_va[c] + 1e-5f);
    vs[cc] = iv; vsh[cc] = v_b[c] * iv + v_be[c] - v_m[c] * iv;
  }

  const float* srcA = f1 + (size_t)b * 256 * 4096;
  const float* srcB = f2 + (size_t)b * 256 * 4096;

  float4 rA[2][2], rB[2][2];
  const int row0 = t >> 4;
  const int row1 = 16 + (t >> 4);
  const int grp  = t & 15;

  const int wseg = t / 18;
  const int wkk  = t - wseg * 18;
  const float* wptr = (wseg < 2) ? q_w : ((wseg < 4) ? k_w : v_w);
  const int wbase0 = (co0 + (wseg & 1)) * 256 * 9 + wkk;
  float wreg = 0.f;

  #define LOADREGS(R)                                                         \
    {                                                                         \
      _Pragma("unroll")                                                       \
      for (int s = 0; s < 2; ++s) {                                           \
        const size_t cb = (size_t)((R) * 2 + s) * 4096;                       \
        {                                                                     \
          const int gy = y0 - 1 + row0;                                       \
          float4 a = make_float4(0.f, 0.f, 0.f, 0.f);                         \
          float4 bb = make_float4(0.f, 0.f, 0.f, 0.f);                        \
          if (gy >= 0 && gy <= 63) {                                          \
            a  = *(const float4*)(srcA + cb + gy * 64 + grp * 4);             \
            bb = *(const float4*)(srcB + cb + gy * 64 + grp * 4);             \
          }                                                                   \
          rA[s][0] = a; rB[s][0] = bb;                                        \
        }                                                                     \
        if (t < 32) {                                                         \
          const int gy = y0 - 1 + row1;                                       \
          float4 a = make_float4(0.f, 0.f, 0.f, 0.f);                         \
          float4 bb = make_float4(0.f, 0.f, 0.f, 0.f);                        \
          if (gy >= 0 && gy <= 63) {                                          \
            a  = *(const float4*)(srcA + cb + gy * 64 + grp * 4);             \
            bb = *(const float4*)(srcB + cb + gy * 64 + grp * 4);             \
          }                                                                   \
          rA[s][1] = a; rB[s][1] = bb;                                        \
        }                                                                     \
      }                                                                       \
      if (t < 108) wreg = wptr[wbase0 + (R) * 18];                            \
    }

  float accQ[2][4] = {{0.f}}, accK[2][4] = {{0.f}}, accV[2][4] = {{0.f}};

  LOADREGS(0);

  for (int r = 0; r < 128; ++r) {
    __syncthreads();
    #pragma unroll
    for (int s = 0; s < 2; ++s) {
      *(float4*)(&tA[s][row0 * CTSTR + grp * 4]) = rA[s][0];
      *(float4*)(&tB[s][row0 * CTSTR + grp * 4]) = rB[s][0];
      if (t < 32) {
        *(float4*)(&tA[s][row1 * CTSTR + grp * 4]) = rA[s][1];
        *(float4*)(&tB[s][row1 * CTSTR + grp * 4]) = rB[s][1];
      }
    }
    if (t < 108) wlds[t] = wreg;
    __syncthreads();
    if (r < 127) LOADREGS(r + 1);

    #pragma unroll
    for (int s = 0; s < 2; ++s) {
      #pragma unroll
      for (int ky = 0; ky < 3; ++ky) {
        const float4 a4 = *(const float4*)(&tA[s][(ry + ky) * CTSTR + x0]);
        const float4 b4 = *(const float4*)(&tB[s][(ry + ky) * CTSTR + x0]);
        const float ca[6] = {dpp_left(a4.w), a4.x, a4.y, a4.z, a4.w, dpp_right(a4.x)};
        const float cb[6] = {dpp_left(b4.w), b4.x, b4.y, b4.z, b4.w, dpp_right(b4.x)};
        #pragma unroll
        for (int cc = 0; cc < 2; ++cc) {
          const int wb = cc * 18 + s * 9 + ky * 3;
          const float q0 = wlds[wb],      q1 = wlds[wb + 1],      q2 = wlds[wb + 2];
          const float k0 = wlds[36 + wb], k1 = wlds[36 + wb + 1], k2 = wlds[36 + wb + 2];
          const float v0 = wlds[72 + wb], v1 = wlds[72 + wb + 1], v2 = wlds[72 + wb + 2];
          #pragma unroll
          for (int px = 0; px < 4; ++px) {
            accQ[cc][px] += cb[px] * q0 + cb[px + 1] * q1 + cb[px + 2] * q2;
            accK[cc][px] += ca[px] * k0 + ca[px + 1] * k1 + ca[px + 2] * k2;
            accV[cc][px] += ca[px] * v0 + ca[px + 1] * v1 + ca[px + 2] * v2;
          }
        }
      }
    }
  }

  // epilogue: BN + ReLU.  Q,K channel-major float4; V pixel-major float2.
  const size_t ob = ((size_t)b * 64 + co0) * 4096 + (size_t)(y0 + ry) * 64 + x0;
  #pragma unroll
  for (int cc = 0; cc < 2; ++cc) {
    float4 o;
    o.x = fmaxf(accQ[cc][0] * qs[cc] + qsh[cc], 0.f);
    o.y = fmaxf(accQ[cc][1] * qs[cc] + qsh[cc], 0.f);
    o.z = fmaxf(accQ[cc][2] * qs[cc] + qsh[cc], 0.f);
    o.w = fmaxf(accQ[cc][3] * qs[cc] + qsh[cc], 0.f);
    *(float4*)(qo + ob + (size_t)cc * 4096) = o;
    o.x = fmaxf(accK[cc][0] * ks[cc] + ksh[cc], 0.f);
    o.y = fmaxf(accK[cc][1] * ks[cc] + ksh[cc], 0.f);
    o.z = fmaxf(accK[cc][2] * ks[cc] + ksh[cc], 0.f);
    o.w = fmaxf(accK[cc][3] * ks[cc] + ksh[cc], 0.f);
    *(float4*)(ko + ob + (size_t)cc * 4096) = o;
  }
  const size_t pb = (size_t)b * 4096 + (size_t)(y0 + ry) * 64 + x0;
  #pragma unroll
  for (int px = 0; px < 4; ++px) {
    float2 o2;
    o2.x = fmaxf(accV[0][px] * vs[0] + vsh[0], 0.f);
    o2.y = fmaxf(accV[1][px] * vs[1] + vsh[1], 0.f);
    *(float2*)(vo + (pb + px) * 64 + co0) = o2;
  }
}

// ---------------------------------------------------------------------------
// Flash attention, fp32 — R20 VERBATIM except V staging (pixel-major source,
// straight row copies, conflict-free). Q,K channel-major; V pixel-major;
// f channel-major. 32 q/block, grid 512 = 2 blocks/CU.
__global__ __launch_bounds__(256, 2) void attention_flash_f32(
    const float* __restrict__ q, const float* __restrict__ k,
    const float* __restrict__ v, float* __restrict__ f)
{
  __shared__ float kp_lds[64 * 68];
  __shared__ float vt_lds[64 * 68];
  __shared__ float qt_lds[64 * 36];

  const int lin = blockIdx.x;
  const int b  = (lin & 7) >> 1;
  const int nb = ((lin >> 3) << 1) | (lin & 1);   // 0..127
  const int n0 = nb * 32;

  const int t = threadIdx.x;
  const int mg = t & 15;
  const int ng = t >> 4;    // 0..15

  const float* qb = q + (size_t)b * 64 * 4096;    // channel-major
  const float* kb = k + (size_t)b * 64 * 4096;    // channel-major
  const float* vb = v + (size_t)b * 4096 * 64;    // PIXEL-major

  // ---- stage Q tile [c][n0..n0+31] into qt_lds[c][n], stride 36
  {
    const int nn = t & 7;      // float4 col index (0..7)
    const int c0 = t >> 3;     // 0..31
    #pragma unroll
    for (int p = 0; p < 2; ++p) {
      const int c = c0 + p * 32;
      const float4 val = *(const float4*)(qb + (size_t)c * 4096 + n0 + nn * 4);
      *(float4*)(qt_lds + c * 36 + nn * 4) = val;
    }
  }

  float acc[2][4] = {{0.f}};
  float m_run[2], l_run[2];
  #pragma unroll
  for (int i = 0; i < 2; ++i) { m_run[i] = -1e30f; l_run[i] = 0.f; }

  const int kc = t >> 2;    // K row c (0..63);  V row m (0..63)
  const int kf = t & 3;     // float4 base

  float4 kreg[4], vreg[4];
  #pragma unroll
  for (int r = 0; r < 4; ++r) {
    kreg[r] = *(const float4*)(kb + (size_t)kc * 4096 + (kf + 4 * r) * 4);
    vreg[r] = *(const float4*)(vb + (size_t)kc * 64 + (kf + 4 * r) * 4);
  }

  for (int tile = 0; tile < 64; ++tile) {
    __syncthreads();

    #pragma unroll
    for (int r = 0; r < 4; ++r) {
      *(float4*)(kp_lds + kc * 68 + (kf + 4 * r) * 4) = kreg[r];
      *(float4*)(vt_lds + kc * 68 + (kf + 4 * r) * 4) = vreg[r];  // [m][c] row copy
    }
    __syncthreads();
    if (tile < 63) {
      const int m0 = (tile + 1) * 64;
      #pragma unroll
      for (int r = 0; r < 4; ++r) {
        kreg[r] = *(const float4*)(kb + (size_t)kc * 4096 + m0 + (kf + 4 * r) * 4);
        vreg[r] = *(const float4*)(vb + (size_t)(m0 + kc) * 64 + (kf + 4 * r) * 4);
      }
    }

    // ---- QK: s[i][j] = sum_c Q[c][2ng+i] * K[c][4mg+j]
    float s[2][4] = {{0.f}};
    #pragma unroll 8
    for (int c = 0; c < 64; ++c) {
      const float2 q2 = *(const float2*)(qt_lds + c * 36 + 2 * ng);
      const float4 k4 = *(const float4*)(kp_lds + c * 68 + 4 * mg);
      const float ka[4] = {k4.x, k4.y, k4.z, k4.w};
      #pragma unroll
      for (int j = 0; j < 4; ++j) {
        s[0][j] += q2.x * ka[j];
        s[1][j] += q2.y * ka[j];
      }
    }

    // ---- online softmax (per n-row, across 16 mg-lanes)
    #pragma unroll
    for (int i = 0; i < 2; ++i) {
      float rm = fmaxf(fmaxf(s[i][0], s[i][1]), fmaxf(s[i][2], s[i][3]));
      rm = fmaxf(rm, __shfl_xor(rm, 1));
      rm = fmaxf(rm, __shfl_xor(rm, 2));
      rm = fmaxf(rm, __shfl_xor(rm, 4));
      rm = fmaxf(rm, __shfl_xor(rm, 8));
      const float mn = fmaxf(m_run[i], rm);
      const float al = __expf(m_run[i] - mn);
      m_run[i] = mn;
      float rs = 0.f;
      #pragma unroll
      for (int j = 0; j < 4; ++j) { s[i][j] = __expf(s[i][j] - mn); rs += s[i][j]; }
      rs += __shfl_xor(rs, 1);
      rs += __shfl_xor(rs, 2);
      rs += __shfl_xor(rs, 4);
      rs += __shfl_xor(rs, 8);
      l_run[i] = al * l_run[i] + rs;
      #pragma unroll
      for (int j = 0; j < 4; ++j) acc[i][j] *= al;
    }

    __syncthreads();  // all K reads done before P overwrites kp_lds
    #pragma unroll
    for (int i = 0; i < 2; ++i)
      *(float4*)(kp_lds + (2 * ng + i) * 68 + 4 * mg) =
          make_float4(s[i][0], s[i][1], s[i][2], s[i][3]);
    __syncthreads();

    // ---- PV: acc[i][j] += sum_m P[2ng+i][m] * V[m][4mg+j]
    #pragma unroll 4
    for (int m4 = 0; m4 < 16; ++m4) {
      float pa[2][4], va[4][4];
      #pragma unroll
      for (int i = 0; i < 2; ++i) {
        const float4 p4 = *(const float4*)(kp_lds + (2 * ng + i) * 68 + m4 * 4);
        pa[i][0] = p4.x; pa[i][1] = p4.y; pa[i][2] = p4.z; pa[i][3] = p4.w;
      }
      #pragma unroll
      for (int jm = 0; jm < 4; ++jm) {
        const float4 v4 = *(const float4*)(vt_lds + (m4 * 4 + jm) * 68 + 4 * mg);
        va[jm][0] = v4.x; va[jm][1] = v4.y; va[jm][2] = v4.z; va[jm][3] = v4.w;
      }
      #pragma unroll
      for (int i = 0; i < 2; ++i)
        #pragma unroll
        for (int jm = 0; jm < 4; ++jm)
          #pragma unroll
          for (int j = 0; j < 4; ++j)
            acc[i][j] += pa[i][jm] * va[jm][j];
    }
  }

  // ---- epilogue: normalize, transpose through qt_lds, coalesced store
  __syncthreads();
  #pragma unroll
  for (int i = 0; i < 2; ++i) {
    const float inv = 1.f / l_run[i];
    #pragma unroll
    for (int j = 0; j < 4; ++j)
      qt_lds[(4 * mg + j) * 36 + 2 * ng + i] = acc[i][j] * inv;  // [c][n]
  }
  __syncthreads();
  {
    const int c = t >> 2;   // 0..63
    #pragma unroll
    for (int r = 0; r < 2; ++r) {
      const int f4i = (t & 3) + 4 * r;   // 0..7
      *(float4*)(f + ((size_t)b * 64 + c) * 4096 + n0 + f4i * 4) =
          *(const float4*)(qt_lds + c * 36 + f4i * 4);
    }
  }
}

// ---------------------------------------------------------------------------
// conv_r (unchanged; fin is [b][64 c][4096 px]).
__global__ __launch_bounds__(256, 4) void conv_r_f32(
    const float* __restrict__ fin, const float* __restrict__ w,
    const float* __restrict__ bi, const float* __restrict__ g,
    const float* __restrict__ be, const float* __restrict__ mu,
    const float* __restrict__ va, const float* __restrict__ res,
    float* __restrict__ out)
{
  __shared__ float tA[2][CTSZ];
  __shared__ float wlds[80];

  const int b   = blockIdx.z;
  const int co0 = blockIdx.y * 4;
  const int y0  = blockIdx.x * 16;
  const int t   = threadIdx.x;
  const int ry  = t >> 4;
  const int xg  = t & 15;
  const int x0  = xg * 4;

  float sc[4], sh[4];
  #pragma unroll
  for (int cc = 0; cc < 4; ++cc) {
    const int c = co0 + cc;
    const float iv = g[c] * rsqrtf(va[c] + 1e-5f);
    sc[cc] = iv; sh[cc] = bi[c] * iv + be[c] - mu[c] * iv;
  }

  const float* srcA = fin + (size_t)b * 64 * 4096;
  float4 rA[2][2];
  const int row0 = t >> 4;
  const int row1 = 16 + (t >> 4);
  const int grp  = t & 15;

  const int wseg = t / 18;
  const int wkk  = t - wseg * 18;
  const int wbase0 = (co0 + wseg) * 64 * 9 + wkk;
  float wreg = 0.f;

  #define LOADR(R)                                                            \
    {                                                                         \
      _Pragma("unroll")                                                       \
      for (int s = 0; s < 2; ++s) {                                           \
        const size_t cb = (size_t)((R) * 2 + s) * 4096;                       \
        {                                                                     \
          const int gy = y0 - 1 + row0;                                       \
          float4 a = make_float4(0.f, 0.f, 0.f, 0.f);                         \
          if (gy >= 0 && gy <= 63)                                            \
            a = *(const float4*)(srcA + cb + gy * 64 + grp * 4);              \
          rA[s][0] = a;                                                       \
        }                                                                     \
        if (t < 32) {                                                         \
          const int gy = y0 - 1 + row1;                                       \
          float4 a = make_float4(0.f, 0.f, 0.f, 0.f);                         \
          if (gy >= 0 && gy <= 63)                                            \
            a = *(const float4*)(srcA + cb + gy * 64 + grp * 4);              \
          rA[s][1] = a;                                                       \
        }                                                                     \
      }                                                                       \
      if (t < 72) wreg = w[wbase0 + (R) * 18];                                \
    }

  float acc[4][4] = {{0.f}};
  LOADR(0);

  for (int r = 0; r < 32; ++r) {
    __syncthreads();
    #pragma unroll
    for (int s = 0; s < 2; ++s) {
      *(float4*)(&tA[s][row0 * CTSTR + grp * 4]) = rA[s][0];
      if (t < 32)
        *(float4*)(&tA[s][row1 * CTSTR + grp * 4]) = rA[s][1];
    }
    if (t < 72) wlds[t] = wreg;
    __syncthreads();
    if (r < 31) LOADR(r + 1);

    #pragma unroll
    for (int s = 0; s < 2; ++s) {
      #pragma unroll
      for (int ky = 0; ky < 3; ++ky) {
        const float4 a4 = *(const float4*)(&tA[s][(ry + ky) * CTSTR + x0]);
        const float ca[6] = {dpp_left(a4.w), a4.x, a4.y, a4.z, a4.w, dpp_right(a4.x)};
        #pragma unroll
        for (int cc = 0; cc < 4; ++cc) {
          const int wb = cc * 18 + s * 9 + ky * 3;
          const float w0 = wlds[wb], w1 = wlds[wb + 1], w2 = wlds[wb + 2];
          #pragma unroll
          for (int px = 0; px < 4; ++px)
            acc[cc][px] += ca[px] * w0 + ca[px + 1] * w1 + ca[px + 2] * w2;
        }
      }
    }
  }

  const size_t ob = ((size_t)b * 256 + co0) * 4096 + (size_t)(y0 + ry) * 64 + x0;
  #pragma unroll
  for (int cc = 0; cc < 4; ++cc) {
    const float4 rv = *(const float4*)(res + ob + (size_t)cc * 4096);
    float4 o;
    o.x = rv.x + fmaxf(acc[cc][0] * sc[cc] + sh[cc], 0.f);
    o.y = rv.y + fmaxf(acc[cc][1] * sc[cc] + sh[cc], 0.f);
    o.z = rv.z + fmaxf(acc[cc][2] * sc[cc] + sh[cc], 0.f);
    o.w = rv.w + fmaxf(acc[cc][3] * sc[cc] + sh[cc], 0.f);
    *(float4*)(out + ob + (size_t)cc * 4096) = o;
  }
}

// ---------------------------------------------------------------------------
extern "C" void kernel_launch(void* const* d_in, const int* in_sizes, int n_in,
                              void* d_out, int out_size, void* d_ws, size_t ws_size,
                              hipStream_t stream) {
  const float* f1 = (const float*)d_in[0];
  const float* f2 = (const float*)d_in[1];
  const float* qw = (const float*)d_in[2];  const float* qb = (const float*)d_in[3];
  const float* qg = (const float*)d_in[4];  const float* qbe = (const float*)d_in[5];
  const float* qm = (const float*)d_in[6];  const float* qv = (const float*)d_in[7];
  const float* kw = (const float*)d_in[8];  const float* kb = (const float*)d_in[9];
  const float* kg = (const float*)d_in[10]; const float* kbe = (const float*)d_in[11];
  const float* km = (const float*)d_in[12]; const float* kv = (const float*)d_in[13];
  const float* vw = (const float*)d_in[14]; const float* vb = (const float*)d_in[15];
  const float* vg = (const float*)d_in[16]; const float* vbe = (const float*)d_in[17];
  const float* vm = (const float*)d_in[18]; const float* vv = (const float*)d_in[19];
  const float* rw = (const float*)d_in[20]; const float* rb = (const float*)d_in[21];
  const float* rg = (const float*)d_in[22]; const float* rbe = (const float*)d_in[23];
  const float* rm = (const float*)d_in[24]; const float* rv = (const float*)d_in[25];

  hipStreamCaptureStatus cap = hipStreamCaptureStatusNone;
  unsigned long long capid = 0;
  const hipError_t ce = hipStreamGetCaptureInfo(stream, &cap, &capid);
  const bool capturing = (ce == hipSuccess) && (cap != hipStreamCaptureStatusNone);

  // Workspace: q,k channel-major; v pixel-major; f channel-major. 4 MB each.
  const size_t SZ1 = (size_t)4 * 64 * 4096 * 4;
  float* qp = (float*)d_ws;
  float* kp = (float*)((char*)d_ws + SZ1);
  float* vp = (float*)((char*)d_ws + 2 * SZ1);
  float* fp = (float*)((char*)d_ws + 3 * SZ1);

  convqkv_f32<<<dim3(4, 32, 4), 256, 0, stream>>>(
      f1, f2,
      qw, qb, qg, qbe, qm, qv,
      kw, kb, kg, kbe, km, kv,
      vw, vb, vg, vbe, vm, vv,
      qp, kp, vp);
  attention_flash_f32<<<dim3(512), 256, 0, stream>>>(qp, kp, vp, fp);
  conv_r_f32<<<dim3(4, 64, 4), 256, 0, stream>>>(fp, rw, rb, rg, rbe, rm, rv,
                                                 f1, (float*)d_out);

  if (!capturing) {
    const hipError_t le = hipGetLastError();
    const hipError_t se = hipStreamSynchronize(stream);
    float h[4] = {0, 0, 0, 0};
    (void)hipMemcpy(h, d_out, 16, hipMemcpyDeviceToHost);
    fprintf(stderr,
        "ATHENA_R25 r20+rowcopyV le=%d sync=%d out=[%g %g %g %g]\n",
        (int)le, (int)se, h[0], h[1], h[2], h[3]);
    fflush(stderr);
  }
}

// Round 12
// 905.118 us; speedup vs baseline: 2.9402x; 1.0801x over previous
//
#include <hip/hip_runtime.h>
#include <cstdio>

// ============================================================================
// ROUND 26: revert attention to R20-verbatim (463us proven; R25 showed
// conflicts are noise: LDS cycle model 9600cy/tile/block x2 blocks x64 tiles
// = 512us == measured). Spend the round on convqkv: it is LDS-bound ~2.4x
// and HALF its LDS time is wave-uniform weight broadcasts. Fix: weights read
// via UNIFORM global addresses -> s_load -> SGPR operand in v_fma. Zero
// weight LDS traffic/staging. Batched 54 dwords per s-half (fits SGPR file).
// (R17's 950us was per-LANE VMEM weight loads at 1 block/CU - different.)
// conv_r gets the same treatment. FMA order unchanged -> absmax stable.
// ============================================================================

// Keeps the harness-stub identifier name (unused utility).
__global__ __launch_bounds__(256) void CrossModalityPositionAttention_56556129354448_kernel(
    float* dst, float val, int n)
{
  const int i = blockIdx.x * 256 + threadIdx.x;
  if (i < n) dst[i] = val;
}

// ---------------------------------------------------------------------------
// DPP lane-shift helpers (conv halo).
__device__ __forceinline__ float dpp_left(float x) {
  return __int_as_float(__builtin_amdgcn_update_dpp(
      0, __float_as_int(x), 0x111, 0xF, 0xF, true));   // row_shr:1
}
__device__ __forceinline__ float dpp_right(float x) {
  return __int_as_float(__builtin_amdgcn_update_dpp(
      0, __float_as_int(x), 0x101, 0xF, 0xF, true));   // row_shl:1
}

#define CTROWS 18
#define CTSTR  64
#define CTSZ   (CTROWS * CTSTR)   // 1152 floats

// ---------------------------------------------------------------------------
// Fused q/k/v conv3x3 + BN + ReLU.  All outputs channel-major [b][64][4096].
// grid (4, 32, 4), block 256, 2 blocks/CU.  Weights via uniform s_load.
__global__ __launch_bounds__(256, 2) void convqkv_f32(
    const float* __restrict__ f1, const float* __restrict__ f2,
    const float* __restrict__ q_w, const float* __restrict__ q_b,
    const float* __restrict__ q_g, const float* __restrict__ q_be,
    const float* __restrict__ q_m, const float* __restrict__ q_va,
    const float* __restrict__ k_w, const float* __restrict__ k_b,
    const float* __restrict__ k_g, const float* __restrict__ k_be,
    const float* __restrict__ k_m, const float* __restrict__ k_va,
    const float* __restrict__ v_w, const float* __restrict__ v_b,
    const float* __restrict__ v_g, const float* __restrict__ v_be,
    const float* __restrict__ v_m, const float* __restrict__ v_va,
    float* __restrict__ qo, float* __restrict__ ko, float* __restrict__ vo)
{
  __shared__ float tA[2][CTSZ];
  __shared__ float tB[2][CTSZ];

  const int b   = blockIdx.z;
  const int co0 = blockIdx.y * 2;
  const int y0  = blockIdx.x * 16;
  const int t   = threadIdx.x;
  const int ry  = t >> 4;
  const int xg  = t & 15;
  const int x0  = xg * 4;

  float qs[2], qsh[2], ks[2], ksh[2], vs[2], vsh[2];
  #pragma unroll
  for (int cc = 0; cc < 2; ++cc) {
    const int c = co0 + cc;
    float iv;
    iv = q_g[c] * rsqrtf(q_va[c] + 1e-5f);
    qs[cc] = iv; qsh[cc] = q_b[c] * iv + q_be[c] - q_m[c] * iv;
    iv = k_g[c] * rsqrtf(k_va[c] + 1e-5f);
    ks[cc] = iv; ksh[cc] = k_b[c] * iv + k_be[c] - k_m[c] * iv;
    iv = v_g[c] * rsqrtf(v_va[c] + 1e-5f);
    vs[cc] = iv; vsh[cc] = v_b[c] * iv + v_be[c] - v_m[c] * iv;
  }

  const float* srcA = f1 + (size_t)b * 256 * 4096;
  const float* srcB = f2 + (size_t)b * 256 * 4096;

  float4 rA[2][2], rB[2][2];
  const int row0 = t >> 4;
  const int row1 = 16 + (t >> 4);
  const int grp  = t & 15;

  #define LOADREGS(R)                                                         \
    {                                                                         \
      _Pragma("unroll")                                                       \
      for (int s = 0; s < 2; ++s) {                                           \
        const size_t cb = (size_t)((R) * 2 + s) * 4096;                       \
        {                                                                     \
          const int gy = y0 - 1 + row0;                                       \
          float4 a = make_float4(0.f, 0.f, 0.f, 0.f);                         \
          float4 bb = make_float4(0.f, 0.f, 0.f, 0.f);                        \
          if (gy >= 0 && gy <= 63) {                                          \
            a  = *(const float4*)(srcA + cb + gy * 64 + grp * 4);             \
            bb = *(const float4*)(srcB + cb + gy * 64 + grp * 4);             \
          }                                                                   \
          rA[s][0] = a; rB[s][0] = bb;                                        \
        }                                                                     \
        if (t < 32) {                                                         \
          const int gy = y0 - 1 + row1;                                       \
          float4 a = make_float4(0.f, 0.f, 0.f, 0.f);                         \
          float4 bb = make_float4(0.f, 0.f, 0.f, 0.f);                        \
          if (gy >= 0 && gy <= 63) {                                          \
            a  = *(const float4*)(srcA + cb + gy * 64 + grp * 4);             \
            bb = *(const float4*)(srcB + cb + gy * 64 + grp * 4);             \
          }                                                                   \
          rA[s][1] = a; rB[s][1] = bb;                                        \
        }                                                                     \
      }                                                                       \
    }

  float accQ[2][4] = {{0.f}}, accK[2][4] = {{0.f}}, accV[2][4] = {{0.f}};

  LOADREGS(0);

  for (int r = 0; r < 128; ++r) {
    __syncthreads();
    #pragma unroll
    for (int s = 0; s < 2; ++s) {
      *(float4*)(&tA[s][row0 * CTSTR + grp * 4]) = rA[s][0];
      *(float4*)(&tB[s][row0 * CTSTR + grp * 4]) = rB[s][0];
      if (t < 32) {
        *(float4*)(&tA[s][row1 * CTSTR + grp * 4]) = rA[s][1];
        *(float4*)(&tB[s][row1 * CTSTR + grp * 4]) = rB[s][1];
      }
    }
    __syncthreads();
    if (r < 127) LOADREGS(r + 1);

    #pragma unroll
    for (int s = 0; s < 2; ++s) {
      // ---- weights for this (round, s): 54 floats, WAVE-UNIFORM addresses
      // -> scalar loads into SGPRs; v_fma consumes the SGPR operand directly.
      const size_t wb = (size_t)co0 * 2304 + (size_t)(r * 2 + s) * 9;
      float wq0[9], wq1[9], wk0[9], wk1[9], wv0[9], wv1[9];
      #pragma unroll
      for (int j = 0; j < 9; ++j) {
        wq0[j] = q_w[wb + j];        wq1[j] = q_w[wb + 2304 + j];
        wk0[j] = k_w[wb + j];        wk1[j] = k_w[wb + 2304 + j];
        wv0[j] = v_w[wb + j];        wv1[j] = v_w[wb + 2304 + j];
      }

      #pragma unroll
      for (int ky = 0; ky < 3; ++ky) {
        const float4 a4 = *(const float4*)(&tA[s][(ry + ky) * CTSTR + x0]);
        const float4 b4 = *(const float4*)(&tB[s][(ry + ky) * CTSTR + x0]);
        const float ca[6] = {dpp_left(a4.w), a4.x, a4.y, a4.z, a4.w, dpp_right(a4.x)};
        const float cb[6] = {dpp_left(b4.w), b4.x, b4.y, b4.z, b4.w, dpp_right(b4.x)};
        const int kb3 = ky * 3;
        #pragma unroll
        for (int px = 0; px < 4; ++px) {
          accQ[0][px] += cb[px] * wq0[kb3] + cb[px + 1] * wq0[kb3 + 1] + cb[px + 2] * wq0[kb3 + 2];
          accK[0][px] += ca[px] * wk0[kb3] + ca[px + 1] * wk0[kb3 + 1] + ca[px + 2] * wk0[kb3 + 2];
          accV[0][px] += ca[px] * wv0[kb3] + ca[px + 1] * wv0[kb3 + 1] + ca[px + 2] * wv0[kb3 + 2];
          accQ[1][px] += cb[px] * wq1[kb3] + cb[px + 1] * wq1[kb3 + 1] + cb[px + 2] * wq1[kb3 + 2];
          accK[1][px] += ca[px] * wk1[kb3] + ca[px + 1] * wk1[kb3 + 1] + ca[px + 2] * wk1[kb3 + 2];
          accV[1][px] += ca[px] * wv1[kb3] + ca[px + 1] * wv1[kb3 + 1] + ca[px + 2] * wv1[kb3 + 2];
        }
      }
    }
  }

  // epilogue: BN + ReLU, channel-major float4 stores (R20 form).
  const size_t ob = ((size_t)b * 64 + co0) * 4096 + (size_t)(y0 + ry) * 64 + x0;
  #pragma unroll
  for (int cc = 0; cc < 2; ++cc) {
    float4 o;
    o.x = fmaxf(accQ[cc][0] * qs[cc] + qsh[cc], 0.f);
    o.y = fmaxf(accQ[cc][1] * qs[cc] + qsh[cc], 0.f);
    o.z = fmaxf(accQ[cc][2] * qs[cc] + qsh[cc], 0.f);
    o.w = fmaxf(accQ[cc][3] * qs[cc] + qsh[cc], 0.f);
    *(float4*)(qo + ob + (size_t)cc * 4096) = o;
    o.x = fmaxf(accK[cc][0] * ks[cc] + ksh[cc], 0.f);
    o.y = fmaxf(accK[cc][1] * ks[cc] + ksh[cc], 0.f);
    o.z = fmaxf(accK[cc][2] * ks[cc] + ksh[cc], 0.f);
    o.w = fmaxf(accK[cc][3] * ks[cc] + ksh[cc], 0.f);
    *(float4*)(ko + ob + (size_t)cc * 4096) = o;
    o.x = fmaxf(accV[cc][0] * vs[cc] + vsh[cc], 0.f);
    o.y = fmaxf(accV[cc][1] * vs[cc] + vsh[cc], 0.f);
    o.z = fmaxf(accV[cc][2] * vs[cc] + vsh[cc], 0.f);
    o.w = fmaxf(accV[cc][3] * vs[cc] + vsh[cc], 0.f);
    *(float4*)(vo + ob + (size_t)cc * 4096) = o;
  }
}

// ---------------------------------------------------------------------------
// Flash attention, fp32 — R20 VERBATIM (463us verified). q,k,v,f all
// channel-major [b][64][4096]. 32 q/block, grid 512 = 2 blocks/CU.
__global__ __launch_bounds__(256, 2) void attention_flash_f32(
    const float* __restrict__ q, const float* __restrict__ k,
    const float* __restrict__ v, float* __restrict__ f)
{
  __shared__ float kp_lds[64 * 68];
  __shared__ float vt_lds[64 * 68];
  __shared__ float qt_lds[64 * 36];

  const int lin = blockIdx.x;
  const int b  = (lin & 7) >> 1;
  const int nb = ((lin >> 3) << 1) | (lin & 1);   // 0..127
  const int n0 = nb * 32;

  const int t = threadIdx.x;
  const int mg = t & 15;
  const int ng = t >> 4;    // 0..15

  const float* qb = q + (size_t)b * 64 * 4096;
  const float* kb = k + (size_t)b * 64 * 4096;
  const float* vb = v + (size_t)b * 64 * 4096;

  {
    const int nn = t & 7;
    const int c0 = t >> 3;
    #pragma unroll
    for (int p = 0; p < 2; ++p) {
      const int c = c0 + p * 32;
      const float4 val = *(const float4*)(qb + (size_t)c * 4096 + n0 + nn * 4);
      *(float4*)(qt_lds + c * 36 + nn * 4) = val;
    }
  }

  float acc[2][4] = {{0.f}};
  float m_run[2], l_run[2];
  #pragma unroll
  for (int i = 0; i < 2; ++i) { m_run[i] = -1e30f; l_run[i] = 0.f; }

  const int kc  = t >> 2;
  const int kf  = t & 3;
  const int vm4 = t & 15;
  const int vc0 = t >> 4;

  float4 kreg[4], vreg[4];
  #pragma unroll
  for (int r = 0; r < 4; ++r)
    kreg[r] = *(const float4*)(kb + (size_t)kc * 4096 + (kf + 4 * r) * 4);
  #pragma unroll
  for (int p = 0; p < 4; ++p)
    vreg[p] = *(const float4*)(vb + (size_t)(vc0 + 16 * p) * 4096 + vm4 * 4);

  for (int tile = 0; tile < 64; ++tile) {
    __syncthreads();

    #pragma unroll
    for (int r = 0; r < 4; ++r)
      *(float4*)(kp_lds + kc * 68 + (kf + 4 * r) * 4) = kreg[r];
    #pragma unroll
    for (int p = 0; p < 4; ++p) {
      const float4 vv = vreg[p];
      const int c = vc0 + 16 * p;
      vt_lds[(vm4 * 4 + 0) * 68 + c] = vv.x;
      vt_lds[(vm4 * 4 + 1) * 68 + c] = vv.y;
      vt_lds[(vm4 * 4 + 2) * 68 + c] = vv.z;
      vt_lds[(vm4 * 4 + 3) * 68 + c] = vv.w;
    }
    __syncthreads();
    if (tile < 63) {
      const int m0 = (tile + 1) * 64;
      #pragma unroll
      for (int r = 0; r < 4; ++r)
        kreg[r] = *(const float4*)(kb + (size_t)kc * 4096 + m0 + (kf + 4 * r) * 4);
      #pragma unroll
      for (int p = 0; p < 4; ++p)
        vreg[p] = *(const float4*)(vb + (size_t)(vc0 + 16 * p) * 4096 + m0 + vm4 * 4);
    }

    float s[2][4] = {{0.f}};
    #pragma unroll 8
    for (int c = 0; c < 64; ++c) {
      const float2 q2 = *(const float2*)(qt_lds + c * 36 + 2 * ng);
      const float4 k4 = *(const float4*)(kp_lds + c * 68 + 4 * mg);
      const float ka[4] = {k4.x, k4.y, k4.z, k4.w};
      #pragma unroll
      for (int j = 0; j < 4; ++j) {
        s[0][j] += q2.x * ka[j];
        s[1][j] += q2.y * ka[j];
      }
    }

    #pragma unroll
    for (int i = 0; i < 2; ++i) {
      float rm = fmaxf(fmaxf(s[i][0], s[i][1]), fmaxf(s[i][2], s[i][3]));
      rm = fmaxf(rm, __shfl_xor(rm, 1));
      rm = fmaxf(rm, __shfl_xor(rm, 2));
      rm = fmaxf(rm, __shfl_xor(rm, 4));
      rm = fmaxf(rm, __shfl_xor(rm, 8));
      const float mn = fmaxf(m_run[i], rm);
      const float al = __expf(m_run[i] - mn);
      m_run[i] = mn;
      float rs = 0.f;
      #pragma unroll
      for (int j = 0; j < 4; ++j) { s[i][j] = __expf(s[i][j] - mn); rs += s[i][j]; }
      rs += __shfl_xor(rs, 1);
      rs += __shfl_xor(rs, 2);
      rs += __shfl_xor(rs, 4);
      rs += __shfl_xor(rs, 8);
      l_run[i] = al * l_run[i] + rs;
      #pragma unroll
      for (int j = 0; j < 4; ++j) acc[i][j] *= al;
    }

    __syncthreads();
    #pragma unroll
    for (int i = 0; i < 2; ++i)
      *(float4*)(kp_lds + (2 * ng + i) * 68 + 4 * mg) =
          make_float4(s[i][0], s[i][1], s[i][2], s[i][3]);
    __syncthreads();

    #pragma unroll 4
    for (int m4 = 0; m4 < 16; ++m4) {
      float pa[2][4], va[4][4];
      #pragma unroll
      for (int i = 0; i < 2; ++i) {
        const float4 p4 = *(const float4*)(kp_lds + (2 * ng + i) * 68 + m4 * 4);
        pa[i][0] = p4.x; pa[i][1] = p4.y; pa[i][2] = p4.z; pa[i][3] = p4.w;
      }
      #pragma unroll
      for (int jm = 0; jm < 4; ++jm) {
        const float4 v4 = *(const float4*)(vt_lds + (m4 * 4 + jm) * 68 + 4 * mg);
        va[jm][0] = v4.x; va[jm][1] = v4.y; va[jm][2] = v4.z; va[jm][3] = v4.w;
      }
      #pragma unroll
      for (int i = 0; i < 2; ++i)
        #pragma unroll
        for (int jm = 0; jm < 4; ++jm)
          #pragma unroll
          for (int j = 0; j < 4; ++j)
            acc[i][j] += pa[i][jm] * va[jm][j];
    }
  }

  __syncthreads();
  #pragma unroll
  for (int i = 0; i < 2; ++i) {
    const float inv = 1.f / l_run[i];
    #pragma unroll
    for (int j = 0; j < 4; ++j)
      qt_lds[(4 * mg + j) * 36 + 2 * ng + i] = acc[i][j] * inv;
  }
  __syncthreads();
  {
    const int c = t >> 2;
    #pragma unroll
    for (int r = 0; r < 2; ++r) {
      const int f4i = (t & 3) + 4 * r;
      *(float4*)(f + ((size_t)b * 64 + c) * 4096 + n0 + f4i * 4) =
          *(const float4*)(qt_lds + c * 36 + f4i * 4);
    }
  }
}

// ---------------------------------------------------------------------------
// conv_r: conv3x3 + BN + ReLU + residual.  Weights via uniform s_load.
// grid (4, 64, 4) = 1024 blocks (4/CU).
__global__ __launch_bounds__(256, 4) void conv_r_f32(
    const float* __restrict__ fin, const float* __restrict__ w,
    const float* __restrict__ bi, const float* __restrict__ g,
    const float* __restrict__ be, const float* __restrict__ mu,
    const float* __restrict__ va, const float* __restrict__ res,
    float* __restrict__ out)
{
  __shared__ float tA[2][CTSZ];

  const int b   = blockIdx.z;
  const int co0 = blockIdx.y * 4;
  const int y0  = blockIdx.x * 16;
  const int t   = threadIdx.x;
  const int ry  = t >> 4;
  const int xg  = t & 15;
  const int x0  = xg * 4;

  float sc[4], sh[4];
  #pragma unroll
  for (int cc = 0; cc < 4; ++cc) {
    const int c = co0 + cc;
    const float iv = g[c] * rsqrtf(va[c] + 1e-5f);
    sc[cc] = iv; sh[cc] = bi[c] * iv + be[c] - mu[c] * iv;
  }

  const float* srcA = fin + (size_t)b * 64 * 4096;
  float4 rA[2][2];
  const int row0 = t >> 4;
  const int row1 = 16 + (t >> 4);
  const int grp  = t & 15;

  #define LOADR(R)                                                            \
    {                                                                         \
      _Pragma("unroll")                                                       \
      for (int s = 0; s < 2; ++s) {                                           \
        const size_t cb = (size_t)((R) * 2 + s) * 4096;                       \
        {                                                                     \
          const int gy = y0 - 1 + row0;                                       \
          float4 a = make_float4(0.f, 0.f, 0.f, 0.f);                         \
          if (gy >= 0 && gy <= 63)                                            \
            a = *(const float4*)(srcA + cb + gy * 64 + grp * 4);              \
          rA[s][0] = a;                                                       \
        }                                                                     \
        if (t < 32) {                                                         \
          const int gy = y0 - 1 + row1;                                       \
          float4 a = make_float4(0.f, 0.f, 0.f, 0.f);                         \
          if (gy >= 0 && gy <= 63)                                            \
            a = *(const float4*)(srcA + cb + gy * 64 + grp * 4);              \
          rA[s][1] = a;                                                       \
        }                                                                     \
      }                                                                       \
    }

  float acc[4][4] = {{0.f}};
  LOADR(0);

  for (int r = 0; r < 32; ++r) {
    __syncthreads();
    #pragma unroll
    for (int s = 0; s < 2; ++s) {
      *(float4*)(&tA[s][row0 * CTSTR + grp * 4]) = rA[s][0];
      if (t < 32)
        *(float4*)(&tA[s][row1 * CTSTR + grp * 4]) = rA[s][1];
    }
    __syncthreads();
    if (r < 31) LOADR(r + 1);

    #pragma unroll
    for (int s = 0; s < 2; ++s) {
      // weights for this (round, s): 36 floats, wave-uniform -> s_load.
      const size_t wb = (size_t)co0 * 576 + (size_t)(r * 2 + s) * 9;
      float w0_[9], w1_[9], w2_[9], w3_[9];
      #pragma unroll
      for (int j = 0; j < 9; ++j) {
        w0_[j] = w[wb + j];
        w1_[j] = w[wb + 576 + j];
        w2_[j] = w[wb + 1152 + j];
        w3_[j] = w[wb + 1728 + j];
      }

      #pragma unroll
      for (int ky = 0; ky < 3; ++ky) {
        const float4 a4 = *(const float4*)(&tA[s][(ry + ky) * CTSTR + x0]);
        const float ca[6] = {dpp_left(a4.w), a4.x, a4.y, a4.z, a4.w, dpp_right(a4.x)};
        const int kb3 = ky * 3;
        #pragma unroll
        for (int px = 0; px < 4; ++px) {
          acc[0][px] += ca[px] * w0_[kb3] + ca[px + 1] * w0_[kb3 + 1] + ca[px + 2] * w0_[kb3 + 2];
          acc[1][px] += ca[px] * w1_[kb3] + ca[px + 1] * w1_[kb3 + 1] + ca[px + 2] * w1_[kb3 + 2];
          acc[2][px] += ca[px] * w2_[kb3] + ca[px + 1] * w2_[kb3 + 1] + ca[px + 2] * w2_[kb3 + 2];
          acc[3][px] += ca[px] * w3_[kb3] + ca[px + 1] * w3_[kb3 + 1] + ca[px + 2] * w3_[kb3 + 2];
        }
      }
    }
  }

  const size_t ob = ((size_t)b * 256 + co0) * 4096 + (size_t)(y0 + ry) * 64 + x0;
  #pragma unroll
  for (int cc = 0; cc < 4; ++cc) {
    const float4 rv = *(const float4*)(res + ob + (size_t)cc * 4096);
    float4 o;
    o.x = rv.x + fmaxf(acc[cc][0] * sc[cc] + sh[cc], 0.f);
    o.y = rv.y + fmaxf(acc[cc][1] * sc[cc] + sh[cc], 0.f);
    o.z = rv.z + fmaxf(acc[cc][2] * sc[cc] + sh[cc], 0.f);
    o.w = rv.w + fmaxf(acc[cc][3] * sc[cc] + sh[cc], 0.f);
    *(float4*)(out + ob + (size_t)cc * 4096) = o;
  }
}

// ---------------------------------------------------------------------------
extern "C" void kernel_launch(void* const* d_in, const int* in_sizes, int n_in,
                              void* d_out, int out_size, void* d_ws, size_t ws_size,
                              hipStream_t stream) {
  const float* f1 = (const float*)d_in[0];
  const float* f2 = (const float*)d_in[1];
  const float* qw = (const float*)d_in[2];  const float* qb = (const float*)d_in[3];
  const float* qg = (const float*)d_in[4];  const float* qbe = (const float*)d_in[5];
  const float* qm = (const float*)d_in[6];  const float* qv = (const float*)d_in[7];
  const float* kw = (const float*)d_in[8];  const float* kb = (const float*)d_in[9];
  const float* kg = (const float*)d_in[10]; const float* kbe = (const float*)d_in[11];
  const float* km = (const float*)d_in[12]; const float* kv = (const float*)d_in[13];
  const float* vw = (const float*)d_in[14]; const float* vb = (const float*)d_in[15];
  const float* vg = (const float*)d_in[16]; const float* vbe = (const float*)d_in[17];
  const float* vm = (const float*)d_in[18]; const float* vv = (const float*)d_in[19];
  const float* rw = (const float*)d_in[20]; const float* rb = (const float*)d_in[21];
  const float* rg = (const float*)d_in[22]; const float* rbe = (const float*)d_in[23];
  const float* rm = (const float*)d_in[24]; const float* rv = (const float*)d_in[25];

  hipStreamCaptureStatus cap = hipStreamCaptureStatusNone;
  unsigned long long capid = 0;
  const hipError_t ce = hipStreamGetCaptureInfo(stream, &cap, &capid);
  const bool capturing = (ce == hipSuccess) && (cap != hipStreamCaptureStatusNone);

  // Workspace: q,k,v,f fp32 [4][64][4096] channel-major, 4 MB each.
  const size_t SZ1 = (size_t)4 * 64 * 4096 * 4;
  float* qp = (float*)d_ws;
  float* kp = (float*)((char*)d_ws + SZ1);
  float* vp = (float*)((char*)d_ws + 2 * SZ1);
  float* fp = (float*)((char*)d_ws + 3 * SZ1);

  convqkv_f32<<<dim3(4, 32, 4), 256, 0, stream>>>(
      f1, f2,
      qw, qb, qg, qbe, qm, qv,
      kw, kb, kg, kbe, km, kv,
      vw, vb, vg, vbe, vm, vv,
      qp, kp, vp);
  attention_flash_f32<<<dim3(512), 256, 0, stream>>>(qp, kp, vp, fp);
  conv_r_f32<<<dim3(4, 64, 4), 256, 0, stream>>>(fp, rw, rb, rg, rbe, rm, rv,
                                                 f1, (float*)d_out);

  if (!capturing) {
    const hipError_t le = hipGetLastError();
    const hipError_t se = hipStreamSynchronize(stream);
    float h[4] = {0, 0, 0, 0};
    (void)hipMemcpy(h, d_out, 16, hipMemcpyDeviceToHost);
    fprintf(stderr,
        "ATHENA_R26 sload-weights le=%d sync=%d out=[%g %g %g %g]\n",
        (int)le, (int)se, h[0], h[1], h[2], h[3]);
    fflush(stderr);
  }
}